// Round 10
// baseline (240.805 us; speedup 1.0000x reference)
//
#include <hip/hip_runtime.h>
#include <hip/hip_bf16.h>

// ModalAttention fused pipeline, MI355X (gfx950).
//
// Math: attn/|global_min| followed by L2-normalize cancels any positive
// per-tensor scale (incl. /sqrt(h)) -> softmax input = s_row/||s_row||_2,
// s = q.k. No global-min reduction needed.
//
// Round 10: qkv = faithful m201-style schedule. 256x256 tile, BK=64,
// 2-buffer LDS (2 x 64KB), 8 waves (2Mx4N), per-wave C = 128x64.
// Per K-tile: 4 quadrant phases of 16 MFMA; B-frags read ONCE at phase 0
// (32 VGPR, reused phases 1-3); A-frags 4 reads/phase; ALL 8 staging
// loads for K-tile t+1 issued at phase 0 (3-phase lead >= HBM latency);
// single vmcnt(0) gate at end of phase 3 (should not wait). 2 barriers
// per phase isolate MFMA under setprio(1). Swizzle: 16B chunk ^ (row&7)
// (128B rows -> bank depends on chunk only -> 2 lanes/bank = free);
// stage side pre-swizzled per-lane constant (r5-verified involution).

typedef __bf16 bf16x8 __attribute__((ext_vector_type(8)));
typedef float f32x4 __attribute__((ext_vector_type(4)));

struct alignas(16) US8 { unsigned short s[8]; };
struct alignas(8)  US4 { unsigned short s[4]; };

// ---------------- workspace layout (bytes) ----------------
#define WS_XB   0ull                        // data bf16  [16384][1024]  33.55MB
#define WS_WB   33554432ull                 // wq,wk,wv bf16 [3][1024][1024] 6.29MB
#define WS_Q    39845888ull                 // Q bf16 [16384][1024] 33.55MB
#define WS_K    73400320ull                 // K bf16 [16384][1024] 33.55MB
#define WS_VT   106954752ull                // V^T bf16 [32][1024][512] 33.55MB
#define WS_S    140509184ull                // S bf16 [16384][512] 16.78MB
#define WS_P    157286400ull                // P bf16 [16384][512] 16.78MB
#define WS_NEED 174063616ull
#define WS_O    WS_Q                        // O bf16 [16384][1024] reuses Q

__device__ __forceinline__ unsigned short f32_to_bf16(float f) {
  unsigned int u = __builtin_bit_cast(unsigned int, f);
  u += 0x7fffu + ((u >> 16) & 1u);            // round-to-nearest-even
  return (unsigned short)(u >> 16);
}
__device__ __forceinline__ float bf16_to_f32(unsigned short h) {
  return __builtin_bit_cast(float, (unsigned int)h << 16);
}

__device__ __forceinline__ void gload_lds16(const void* g, void* lds) {
  __builtin_amdgcn_global_load_lds(
      (const __attribute__((address_space(1))) unsigned int*)g,
      (__attribute__((address_space(3))) unsigned int*)lds, 16, 0, 0);
}

__device__ __forceinline__ float wave_sum(float v) {
#pragma unroll
  for (int off = 32; off > 0; off >>= 1) v += __shfl_xor(v, off);
  return v;
}
__device__ __forceinline__ float wave_max(float v) {
#pragma unroll
  for (int off = 32; off > 0; off >>= 1) v = fmaxf(v, __shfl_xor(v, off));
  return v;
}

// ---------------- f32 -> bf16 cast ----------------
__global__ __launch_bounds__(256) void cvt_f32_bf16(const float* __restrict__ src,
                                                    unsigned short* __restrict__ dst,
                                                    int n8) {
  int i = blockIdx.x * 256 + threadIdx.x;
  if (i >= n8) return;
  const float4* sp = (const float4*)(src + (size_t)i * 8);
  float4 a = sp[0], b = sp[1];
  US8 u;
  u.s[0] = f32_to_bf16(a.x); u.s[1] = f32_to_bf16(a.y);
  u.s[2] = f32_to_bf16(a.z); u.s[3] = f32_to_bf16(a.w);
  u.s[4] = f32_to_bf16(b.x); u.s[5] = f32_to_bf16(b.y);
  u.s[6] = f32_to_bf16(b.z); u.s[7] = f32_to_bf16(b.w);
  *(US8*)(dst + (size_t)i * 8) = u;
}

// ============ QKV: m201-style 256x256, BK=64, 2-buf, N=3072 ============
// M=16384, K=1024 = 16 K-tiles of 64. Grid 768 x 512 threads.
// LDS buf (64KB): A-h0 [0,16K) A-h1 [16K,32K) B-h0 [32K,48K) B-h1 [48K,64K);
// half = 128 rows x 64 bf16 (128B rows), chunk-swizzled.
__global__ __launch_bounds__(512, 2) void qkv_m2(
    const unsigned short* __restrict__ Xb, const unsigned short* __restrict__ Wb,
    unsigned short* __restrict__ Q, unsigned short* __restrict__ Kb,
    unsigned short* __restrict__ Vt) {
  __shared__ char smc[2][65536];

  const int tid = threadIdx.x;
  const int w = tid >> 6, lane = tid & 63;
  const int wm = w >> 2, wn = w & 3;
  const int lr = lane & 15, lk4 = lane >> 4;

  // bijective XCD-chunked swizzle: 768 blocks, 96 per XCD
  const int bid = blockIdx.x;
  const int wg = (bid & 7) * 96 + (bid >> 3);
  const int bm = wg / 12, bn = wg % 12;

  const char* Ag = (const char*)(Xb + (size_t)bm * 256 * 1024);
  const char* Bg = (const char*)(Wb + (size_t)bn * 256 * 1024);

  // stage: thread writes LDS phys off (h*16K + j*8K + tid*16) -> row =
  // h*128 + j*64 + (tid>>3), phys chunk = tid&7; src chunk = phys ^ (row&7)
  const int srow = tid >> 3;                        // 0..63
  const int sch  = ((tid & 7) ^ (srow & 7)) * 16;   // per-lane const

  const char* pS[8];
#pragma unroll
  for (int h = 0; h < 2; ++h)
#pragma unroll
    for (int j = 0; j < 2; ++j) {
      pS[h * 2 + j]     = Ag + (size_t)(h * 128 + j * 64 + srow) * 2048 + sch;
      pS[4 + h * 2 + j] = Bg + (size_t)(h * 128 + j * 64 + srow) * 2048 + sch;
    }

  // read: A row = wm*128 + m*16 + lr (half wm); B row = wn*64 + n*16 + lr
  // (half wn>>1, in-half base (wn&1)*64). chunk wanted = ks*4 + lk4,
  // phys = chunk ^ (row&7), row&7 = lr&7.
  const int rAoff = wm * 16384;
  const int rBoff = 32768 + (wn >> 1) * 16384 + (wn & 1) * 8192;
  const int rowb  = lr * 128;
  const int ck0 = ((lk4) ^ (lr & 7)) * 16;         // ks=0
  const int ck1 = ((4 + lk4) ^ (lr & 7)) * 16;     // ks=1

  f32x4 acc[8][4] = {};
  bf16x8 av[2][2], bv[2][4];

#define STAGE_ALL(OBUF)                                                       \
  do {                                                                        \
    char* db = (char*)smc[OBUF] + tid * 16;                                   \
    gload_lds16(pS[0], db);                                                   \
    gload_lds16(pS[1], db + 8192);                                            \
    gload_lds16(pS[2], db + 16384);                                           \
    gload_lds16(pS[3], db + 24576);                                           \
    gload_lds16(pS[4], db + 32768);                                           \
    gload_lds16(pS[5], db + 40960);                                           \
    gload_lds16(pS[6], db + 49152);                                           \
    gload_lds16(pS[7], db + 57344);                                           \
    _Pragma("unroll") for (int q = 0; q < 8; ++q) pS[q] += 128;               \
  } while (0)

#define RD_A(BUF, M, KS) \
  (*(const bf16x8*)(smc[BUF] + rAoff + (M) * 2048 + rowb + ((KS) ? ck1 : ck0)))
#define RD_B(BUF, N, KS) \
  (*(const bf16x8*)(smc[BUF] + rBoff + (N) * 2048 + rowb + ((KS) ? ck1 : ck0)))

#define MFMA_Q(QQ)                                                            \
  __builtin_amdgcn_s_setprio(1);                                              \
  _Pragma("unroll") for (int ks = 0; ks < 2; ++ks)                            \
      _Pragma("unroll") for (int mm = 0; mm < 2; ++mm)                        \
          _Pragma("unroll") for (int nn = 0; nn < 4; ++nn)                    \
              acc[2 * (QQ) + mm][nn] = __builtin_amdgcn_mfma_f32_16x16x32_bf16( \
                  av[ks][mm], bv[ks][nn], acc[2 * (QQ) + mm][nn], 0, 0, 0);   \
  __builtin_amdgcn_s_setprio(0);

  // phase 0: 12 ds_reads (B all + A quad0) + all 8 staging loads of t+1
#define KPH0(BUF, OBUF, DO_STAGE)                                             \
  do {                                                                        \
    _Pragma("unroll") for (int ks = 0; ks < 2; ++ks)                          \
        _Pragma("unroll") for (int nn = 0; nn < 4; ++nn)                      \
            bv[ks][nn] = RD_B(BUF, nn, ks);                                   \
    av[0][0] = RD_A(BUF, 0, 0); av[0][1] = RD_A(BUF, 1, 0);                   \
    av[1][0] = RD_A(BUF, 0, 1); av[1][1] = RD_A(BUF, 1, 1);                   \
    if (DO_STAGE) STAGE_ALL(OBUF);                                            \
    __builtin_amdgcn_sched_barrier(0);                                        \
    __builtin_amdgcn_s_barrier();                                             \
    asm volatile("s_waitcnt lgkmcnt(0)" ::: "memory");                        \
    __builtin_amdgcn_sched_barrier(0);                                        \
    MFMA_Q(0)                                                                 \
    __builtin_amdgcn_sched_barrier(0);                                        \
    __builtin_amdgcn_s_barrier();                                             \
  } while (0)

  // phases 1-3: 4 A reads; phase 3 carries the vmcnt(0) gate (3-phase lead)
#define KPHQ(BUF, QQ, GATE)                                                   \
  do {                                                                        \
    av[0][0] = RD_A(BUF, 2 * (QQ), 0); av[0][1] = RD_A(BUF, 2 * (QQ) + 1, 0); \
    av[1][0] = RD_A(BUF, 2 * (QQ), 1); av[1][1] = RD_A(BUF, 2 * (QQ) + 1, 1); \
    __builtin_amdgcn_sched_barrier(0);                                        \
    __builtin_amdgcn_s_barrier();                                             \
    asm volatile("s_waitcnt lgkmcnt(0)" ::: "memory");                        \
    __builtin_amdgcn_sched_barrier(0);                                        \
    MFMA_Q(QQ)                                                                \
    __builtin_amdgcn_sched_barrier(0);                                        \
    if (GATE) { asm volatile("s_waitcnt vmcnt(0)" ::: "memory"); }            \
    __builtin_amdgcn_s_barrier();                                             \
  } while (0)

#define KTILE(BUF, OBUF, DO_STAGE)                                            \
  do {                                                                        \
    KPH0(BUF, OBUF, DO_STAGE);                                                \
    KPHQ(BUF, 1, 0);                                                          \
    KPHQ(BUF, 2, 0);                                                          \
    KPHQ(BUF, 3, DO_STAGE);                                                   \
  } while (0)

  // prologue: stage K-tile 0 into buf0, drain, barrier
  STAGE_ALL(0);
  asm volatile("s_waitcnt vmcnt(0)" ::: "memory");
  __builtin_amdgcn_s_barrier();
  __builtin_amdgcn_sched_barrier(0);

  // K-tiles 0..15; t stages t+1 into the other buffer (t<=14)
  for (int i = 0; i < 7; ++i) {
    KTILE(0, 1, 1);
    KTILE(1, 0, 1);
  }
  KTILE(0, 1, 1);   // t=14 stages t=15
  KTILE(1, 0, 0);   // t=15

#undef KTILE
#undef KPHQ
#undef KPH0
#undef MFMA_Q
#undef RD_B
#undef RD_A
#undef STAGE_ALL

  // epilogue: C fragment (row = base + (lane>>4)*4 + i, col = base + (lane&15))
  const int cr = lk4 << 2;
  const int z = bn >> 2;                       // 0=Q 1=K 2=V
  const int gr0 = bm * 256 + wm * 128;
  const int gc0 = (bn & 3) * 256 + wn * 64;
  if (z < 2) {
    unsigned short* C = (z == 0) ? Q : Kb;
#pragma unroll
    for (int m = 0; m < 8; ++m)
#pragma unroll
      for (int n = 0; n < 4; ++n)
#pragma unroll
        for (int i = 0; i < 4; ++i)
          C[(size_t)(gr0 + m * 16 + cr + i) * 1024 + (gc0 + n * 16 + lr)] =
              f32_to_bf16(acc[m][n][i]);
  } else {
    // Vt[b][d][t] = V[b*512+t][d]; 4 consecutive t per lane -> 8B store
#pragma unroll
    for (int m = 0; m < 8; ++m) {
      const int gr = gr0 + m * 16 + cr;
      const int b = gr >> 9, tt = gr & 511;
#pragma unroll
      for (int n = 0; n < 4; ++n) {
        const int d = gc0 + n * 16 + lr;
        US4 u;
        u.s[0] = f32_to_bf16(acc[m][n][0]);
        u.s[1] = f32_to_bf16(acc[m][n][1]);
        u.s[2] = f32_to_bf16(acc[m][n][2]);
        u.s[3] = f32_to_bf16(acc[m][n][3]);
        *(US4*)(Vt + ((size_t)b * 1024 + d) * 512 + tt) = u;
      }
    }
  }
}

// ---------------- shared BT-GEMM core (m97 structure + XOR swizzle) ----------
__device__ __forceinline__ void gemm_bt_core(const unsigned short* __restrict__ A,
                                             const unsigned short* __restrict__ B,
                                             int lda, int ldb, int K,
                                             unsigned short* As, unsigned short* Bs,
                                             f32x4 acc[4][4]) {
  const int tid = threadIdx.x;
  const int w = tid >> 6, lane = tid & 63;
  const int wr = w >> 1, wc = w & 1;
  const int lr = lane & 15;
  const int lk = (((lane >> 4) ^ ((lr >> 1) & 3))) << 3;
  const int k8 = (((lane & 3) ^ ((lane >> 3) & 3))) << 3;

  for (int kk = 0; kk < K; kk += 32) {
#pragma unroll
    for (int j = 0; j < 2; ++j) {
      const int i = (w << 1) + j;            // 0..7 wave-load id
      const int c = (i << 6) + lane;         // 16B chunk id, 512 per tile
      const int r = c >> 2;                  // tile row 0..127
      gload_lds16(A + (size_t)r * lda + kk + k8, As + (i << 9));
      gload_lds16(B + (size_t)r * ldb + kk + k8, Bs + (i << 9));
    }
    __syncthreads();                         // drains vmcnt for all waves
    bf16x8 av[4], bv[4];
#pragma unroll
    for (int m = 0; m < 4; ++m)
      av[m] = *(const bf16x8*)(As + (((wr << 6) + (m << 4) + lr) << 5) + lk);
#pragma unroll
    for (int n = 0; n < 4; ++n)
      bv[n] = *(const bf16x8*)(Bs + (((wc << 6) + (n << 4) + lr) << 5) + lk);
#pragma unroll
    for (int m = 0; m < 4; ++m)
#pragma unroll
      for (int n = 0; n < 4; ++n)
        acc[m][n] = __builtin_amdgcn_mfma_f32_16x16x32_bf16(av[m], bv[n], acc[m][n], 0, 0, 0);
    __syncthreads();
  }
}

// ---------------- S = Q K^T per batch (bf16 out) ----------------
__global__ __launch_bounds__(256) void s_gemm(const unsigned short* __restrict__ Q,
                                              const unsigned short* __restrict__ Kb,
                                              unsigned short* __restrict__ S) {
  __shared__ unsigned short As[4096];
  __shared__ unsigned short Bs[4096];
  const int bn = blockIdx.x, bm = blockIdx.y, b = blockIdx.z;
  const unsigned short* A = Q + ((size_t)b * 512 + bm * 128) * 1024;
  const unsigned short* B = Kb + ((size_t)b * 512 + bn * 128) * 1024;
  f32x4 acc[4][4] = {};
  gemm_bt_core(A, B, 1024, 1024, 1024, As, Bs, acc);

  const int tid = threadIdx.x;
  const int w = tid >> 6, lane = tid & 63;
  const int wr = w >> 1, wc = w & 1;
  const int cr = (lane >> 4) << 2;
  const int cc = lane & 15;
  unsigned short* Cp = S + (size_t)b * 262144;
  const int rbase = bm * 128 + wr * 64;
  const int cbase = bn * 128 + wc * 64;
#pragma unroll
  for (int m = 0; m < 4; ++m)
#pragma unroll
    for (int n = 0; n < 4; ++n)
#pragma unroll
      for (int i = 0; i < 4; ++i)
        Cp[(size_t)(rbase + m * 16 + cr + i) * 512 + (cbase + n * 16 + cc)] =
            f32_to_bf16(acc[m][n][i]);
}

// ---------------- row L2-normalize + softmax; write attn f32 + P bf16 -------
__global__ __launch_bounds__(256) void softmax_rows(const unsigned short* __restrict__ S,
                                                    float* __restrict__ out,
                                                    unsigned short* __restrict__ P) {
  const int w = threadIdx.x >> 6, lane = threadIdx.x & 63;
  const int r = blockIdx.x * 4 + w;          // global row 0..16383
  const int b = r >> 9, s = r & 511;
  US8 v = *(const US8*)(S + (size_t)r * 512 + lane * 8);
  float x[8];
#pragma unroll
  for (int i = 0; i < 8; ++i) x[i] = bf16_to_f32(v.s[i]);
  float ss = 0.f;
#pragma unroll
  for (int i = 0; i < 8; ++i) ss += x[i] * x[i];
  ss = wave_sum(ss);
  const float inv = 1.0f / fmaxf(sqrtf(ss), 1e-12f);
  float mx = -1e30f;
#pragma unroll
  for (int i = 0; i < 8; ++i) { x[i] *= inv; mx = fmaxf(mx, x[i]); }
  mx = wave_max(mx);
  float se = 0.f;
#pragma unroll
  for (int i = 0; i < 8; ++i) { x[i] = __expf(x[i] - mx); se += x[i]; }
  se = wave_sum(se);
  const float rs = 1.0f / se;
#pragma unroll
  for (int i = 0; i < 8; ++i) x[i] *= rs;

  float* op = out + (size_t)b * 786432 + 524288 + (size_t)s * 512 + lane * 8;
  float4 o0 = {x[0], x[1], x[2], x[3]};
  float4 o1 = {x[4], x[5], x[6], x[7]};
  *(float4*)op = o0;
  *(float4*)(op + 4) = o1;
  US8 u;
#pragma unroll
  for (int i = 0; i < 8; ++i) u.s[i] = f32_to_bf16(x[i]);
  *(US8*)(P + (size_t)r * 512 + lane * 8) = u;
}

// ---------------- O = P * V (via Vt, BT layout), bf16 out ----------------
__global__ __launch_bounds__(256) void pv_gemm(const unsigned short* __restrict__ P,
                                               const unsigned short* __restrict__ Vt,
                                               unsigned short* __restrict__ O) {
  __shared__ unsigned short As[4096];
  __shared__ unsigned short Bs[4096];
  const int bn = blockIdx.x, bm = blockIdx.y, b = blockIdx.z;
  const unsigned short* A = P + ((size_t)b * 512 + bm * 128) * 512;
  const unsigned short* B = Vt + ((size_t)b * 1024 + bn * 128) * 512;
  f32x4 acc[4][4] = {};
  gemm_bt_core(A, B, 512, 512, 512, As, Bs, acc);

  const int tid = threadIdx.x;
  const int w = tid >> 6, lane = tid & 63;
  const int wr = w >> 1, wc = w & 1;
  const int cr = (lane >> 4) << 2;
  const int cc = lane & 15;
  const int grow = b * 512 + bm * 128 + wr * 64;
  const int cbase = bn * 128 + wc * 64;
#pragma unroll
  for (int m = 0; m < 4; ++m)
#pragma unroll
    for (int n = 0; n < 4; ++n)
#pragma unroll
      for (int i = 0; i < 4; ++i)
        O[(size_t)(grow + m * 16 + cr + i) * 1024 + (cbase + n * 16 + cc)] =
            f32_to_bf16(acc[m][n][i]);
}

// ---------------- residual + LayerNorm, wave per row ----------------
__global__ __launch_bounds__(256) void ln_rows(const unsigned short* __restrict__ O,
                                               const unsigned short* __restrict__ Xb,
                                               const float* __restrict__ gamma,
                                               const float* __restrict__ beta,
                                               float* __restrict__ out) {
  const int w = threadIdx.x >> 6, lane = threadIdx.x & 63;
  const int r = blockIdx.x * 4 + w;
  const int b = r >> 9, s = r & 511;
  const unsigned short* orow = O + (size_t)r * 1024;
  const unsigned short* drow = Xb + (size_t)r * 1024;
  float x[16];
  float sm = 0.f, sq = 0.f;
#pragma unroll
  for (int j = 0; j < 4; ++j) {
    const int col = j * 256 + lane * 4;
    US4 o4 = *(const US4*)(orow + col);
    US4 d4 = *(const US4*)(drow + col);
    x[j * 4 + 0] = bf16_to_f32(o4.s[0]) + bf16_to_f32(d4.s[0]);
    x[j * 4 + 1] = bf16_to_f32(o4.s[1]) + bf16_to_f32(d4.s[1]);
    x[j * 4 + 2] = bf16_to_f32(o4.s[2]) + bf16_to_f32(d4.s[2]);
    x[j * 4 + 3] = bf16_to_f32(o4.s[3]) + bf16_to_f32(d4.s[3]);
  }
#pragma unroll
  for (int i = 0; i < 16; ++i) { sm += x[i]; sq += x[i] * x[i]; }
  sm = wave_sum(sm);
  sq = wave_sum(sq);
  const float mean = sm * (1.0f / 1024.0f);
  const float var = sq * (1.0f / 1024.0f) - mean * mean;
  const float rstd = rsqrtf(var + 1e-6f);
  float* op = out + (size_t)b * 786432 + (size_t)s * 1024;
#pragma unroll
  for (int j = 0; j < 4; ++j) {
    const int col = j * 256 + lane * 4;
    float4 g4 = *(const float4*)(gamma + col);
    float4 b4 = *(const float4*)(beta + col);
    float4 y;
    y.x = (x[j * 4 + 0] - mean) * rstd * g4.x + b4.x;
    y.y = (x[j * 4 + 1] - mean) * rstd * g4.y + b4.y;
    y.z = (x[j * 4 + 2] - mean) * rstd * g4.z + b4.z;
    y.w = (x[j * 4 + 3] - mean) * rstd * g4.w + b4.w;
    *(float4*)(op + col) = y;
  }
}

extern "C" void kernel_launch(void* const* d_in, const int* in_sizes, int n_in,
                              void* d_out, int out_size, void* d_ws, size_t ws_size,
                              hipStream_t stream) {
  const float* data  = (const float*)d_in[0];
  const float* wq    = (const float*)d_in[1];
  const float* wk    = (const float*)d_in[2];
  const float* wv    = (const float*)d_in[3];
  const float* gamma = (const float*)d_in[4];
  const float* beta  = (const float*)d_in[5];
  float* out = (float*)d_out;
  char* ws = (char*)d_ws;
  if (ws_size < WS_NEED) return;

  unsigned short* Xb = (unsigned short*)(ws + WS_XB);
  unsigned short* Wb = (unsigned short*)(ws + WS_WB);
  unsigned short* Q  = (unsigned short*)(ws + WS_Q);
  unsigned short* Kb = (unsigned short*)(ws + WS_K);
  unsigned short* Vt = (unsigned short*)(ws + WS_VT);
  unsigned short* S  = (unsigned short*)(ws + WS_S);
  unsigned short* P  = (unsigned short*)(ws + WS_P);
  unsigned short* O  = (unsigned short*)(ws + WS_O);

  cvt_f32_bf16<<<8192, 256, 0, stream>>>(data, Xb, 2097152);
  cvt_f32_bf16<<<512, 256, 0, stream>>>(wq, Wb, 131072);
  cvt_f32_bf16<<<512, 256, 0, stream>>>(wk, Wb + 1048576, 131072);
  cvt_f32_bf16<<<512, 256, 0, stream>>>(wv, Wb + 2097152, 131072);
  qkv_m2<<<768, 512, 0, stream>>>(Xb, Wb, Q, Kb, Vt);
  s_gemm<<<dim3(4, 4, 32), 256, 0, stream>>>(Q, Kb, S);
  softmax_rows<<<4096, 256, 0, stream>>>(S, out, P);
  pv_gemm<<<dim3(8, 4, 32), 256, 0, stream>>>(P, Vt, O);
  ln_rows<<<4096, 256, 0, stream>>>(O, Xb, gamma, beta, out);
}